// Round 1
// baseline (162.214 us; speedup 1.0000x reference)
//
#include <hip/hip_runtime.h>
#include <hip/hip_bf16.h>

// Problem constants: N=2048, D=768, H=12, Y=64. W = [Wq;Wk] as [1536][768].
#define NN 2048
#define DD 768
#define HW 1536           // rows of combined W
#define G_ELEMS (2048*768)        // 1572864
#define W1_ELEMS (12*64*768)      // 589824 (Wq flat == WB rows 0..767)

typedef __attribute__((ext_vector_type(8))) short bf16x8;
typedef __attribute__((ext_vector_type(4))) float f32x4;

// ---------------- Kernel 1: fp32 -> bf16 convert (beta folded into Wq) -------
__global__ __launch_bounds__(256) void convert_kernel(
    const float* __restrict__ g, const float* __restrict__ Wq,
    const float* __restrict__ Wk, __hip_bfloat16* __restrict__ gB,
    __hip_bfloat16* __restrict__ wB) {
  int base = (blockIdx.x * 256 + threadIdx.x) * 4;
  float4 v;
  __hip_bfloat16* dst;
  if (base < G_ELEMS) {
    v = *reinterpret_cast<const float4*>(g + base);
    dst = gB + base;
  } else if (base < G_ELEMS + W1_ELEMS) {
    int o = base - G_ELEMS;
    v = *reinterpret_cast<const float4*>(Wq + o);
    v.x *= 0.125f; v.y *= 0.125f; v.z *= 0.125f; v.w *= 0.125f;  // beta
    dst = wB + o;
  } else {
    int o = base - (G_ELEMS + W1_ELEMS);
    v = *reinterpret_cast<const float4*>(Wk + o);
    dst = wB + W1_ELEMS + o;
  }
  __hip_bfloat16 h0 = __float2bfloat16(v.x), h1 = __float2bfloat16(v.y);
  __hip_bfloat16 h2 = __float2bfloat16(v.z), h3 = __float2bfloat16(v.w);
  ushort4 u;
  u.x = *reinterpret_cast<unsigned short*>(&h0);
  u.y = *reinterpret_cast<unsigned short*>(&h1);
  u.z = *reinterpret_cast<unsigned short*>(&h2);
  u.w = *reinterpret_cast<unsigned short*>(&h3);
  *reinterpret_cast<ushort4*>(dst) = u;
}

// ---------------- Kernel 2: QK projection GEMM (bf16 MFMA) -------------------
// C[2048][1536] = gB[2048][768] * wB[1536][768]^T   (both operands k-major)
// 128x128 tile / block(256)=4 waves, each wave 64x64, 4x4 tiles of 16x16x32.
#define LDP 48   // 32 + 16 pad (96B rows: 16B-aligned, breaks 16-way conflicts)
__global__ __launch_bounds__(256) void proj_kernel(
    const __hip_bfloat16* __restrict__ gB, const __hip_bfloat16* __restrict__ wB,
    __hip_bfloat16* __restrict__ QK) {
  __shared__ __align__(16) __hip_bfloat16 As[128 * LDP];
  __shared__ __align__(16) __hip_bfloat16 Bs[128 * LDP];
  const int t = threadIdx.x;
  const int wave = t >> 6, lane = t & 63;
  const int lr = lane & 15, lg = lane >> 4;
  const int wm = wave & 1, wn = wave >> 1;
  const int bm = blockIdx.x, bn = blockIdx.y;

  f32x4 acc[4][4] = {};

  for (int kt = 0; kt < DD; kt += 32) {
    __syncthreads();
#pragma unroll
    for (int i = 0; i < 2; ++i) {
      int c = t + i * 256;          // 512 chunks of 8 bf16
      int row = c >> 2, seg = (c & 3) * 8;
      uint4 va = *reinterpret_cast<const uint4*>(gB + (bm * 128 + row) * DD + kt + seg);
      *reinterpret_cast<uint4*>(&As[row * LDP + seg]) = va;
      uint4 vb = *reinterpret_cast<const uint4*>(wB + (bn * 128 + row) * DD + kt + seg);
      *reinterpret_cast<uint4*>(&Bs[row * LDP + seg]) = vb;
    }
    __syncthreads();
    bf16x8 a[4], b[4];
#pragma unroll
    for (int mt = 0; mt < 4; ++mt)
      a[mt] = *reinterpret_cast<const bf16x8*>(&As[(wm * 64 + mt * 16 + lr) * LDP + lg * 8]);
#pragma unroll
    for (int nt = 0; nt < 4; ++nt)
      b[nt] = *reinterpret_cast<const bf16x8*>(&Bs[(wn * 64 + nt * 16 + lr) * LDP + lg * 8]);
#pragma unroll
    for (int mt = 0; mt < 4; ++mt)
#pragma unroll
      for (int nt = 0; nt < 4; ++nt)
        acc[mt][nt] = __builtin_amdgcn_mfma_f32_16x16x32_bf16(a[mt], b[nt], acc[mt][nt], 0, 0, 0);
  }
  // Epilogue: D mapping col=lane&15, row=(lane>>4)*4+r  [guide §3, m89-verified]
#pragma unroll
  for (int mt = 0; mt < 4; ++mt) {
    int row = bm * 128 + wm * 64 + mt * 16 + lg * 4;
#pragma unroll
    for (int nt = 0; nt < 4; ++nt) {
      int col = bn * 128 + wn * 64 + nt * 16 + lr;
#pragma unroll
      for (int r = 0; r < 4; ++r)
        QK[(row + r) * HW + col] = __float2bfloat16(acc[mt][nt][r]);
    }
  }
}

// ---------------- Kernel 3: per-head scores + online logsumexp ---------------
// grid (32 q-tiles, 12 heads); block 256 = 4 waves; wave w owns q rows w*16..+15
#define LDQ 80   // 64 + 16 pad
__global__ __launch_bounds__(256) void attn_kernel(
    const __hip_bfloat16* __restrict__ QK, float* __restrict__ out) {
  __shared__ __align__(16) __hip_bfloat16 Qs[64 * LDQ];
  __shared__ __align__(16) __hip_bfloat16 Ks[64 * LDQ];
  const int t = threadIdx.x;
  const int wave = t >> 6, lane = t & 63;
  const int lr = lane & 15, lg = lane >> 4;
  const int q0 = blockIdx.x * 64, h = blockIdx.y;

  // stage Q tile [64 q][64 z]
#pragma unroll
  for (int i = 0; i < 2; ++i) {
    int c = t + i * 256;           // 512 chunks
    int row = c >> 3, seg = (c & 7) * 8;
    uint4 v = *reinterpret_cast<const uint4*>(QK + (q0 + row) * HW + h * 64 + seg);
    *reinterpret_cast<uint4*>(&Qs[row * LDQ + seg]) = v;
  }
  __syncthreads();
  bf16x8 aq[2];
#pragma unroll
  for (int z = 0; z < 2; ++z)
    aq[z] = *reinterpret_cast<const bf16x8*>(&Qs[(wave * 16 + lr) * LDQ + z * 32 + lg * 8]);

  float m_run[4], l_run[4];
#pragma unroll
  for (int r = 0; r < 4; ++r) { m_run[r] = -1e30f; l_run[r] = 0.0f; }

  for (int kc = 0; kc < NN; kc += 64) {
    __syncthreads();
#pragma unroll
    for (int i = 0; i < 2; ++i) {
      int c = t + i * 256;
      int row = c >> 3, seg = (c & 7) * 8;
      uint4 v = *reinterpret_cast<const uint4*>(QK + (kc + row) * HW + 768 + h * 64 + seg);
      *reinterpret_cast<uint4*>(&Ks[row * LDQ + seg]) = v;
    }
    __syncthreads();
    f32x4 s[4] = {};
#pragma unroll
    for (int nt = 0; nt < 4; ++nt)
#pragma unroll
      for (int z = 0; z < 2; ++z) {
        bf16x8 b = *reinterpret_cast<const bf16x8*>(&Ks[(nt * 16 + lr) * LDQ + z * 32 + lg * 8]);
        s[nt] = __builtin_amdgcn_mfma_f32_16x16x32_bf16(aq[z], b, s[nt], 0, 0, 0);
      }
    // s[nt][r]: q = wave*16 + lg*4 + r, k = kc + nt*16 + lr (already *beta)
#pragma unroll
    for (int r = 0; r < 4; ++r) {
      float cmax = fmaxf(fmaxf(s[0][r], s[1][r]), fmaxf(s[2][r], s[3][r]));
#pragma unroll
      for (int msk = 1; msk <= 8; msk <<= 1)
        cmax = fmaxf(cmax, __shfl_xor(cmax, msk));
      float m_new = fmaxf(m_run[r], cmax);
      float p = __expf(s[0][r] - m_new) + __expf(s[1][r] - m_new) +
                __expf(s[2][r] - m_new) + __expf(s[3][r] - m_new);
#pragma unroll
      for (int msk = 1; msk <= 8; msk <<= 1)
        p += __shfl_xor(p, msk);
      l_run[r] = l_run[r] * __expf(m_run[r] - m_new) + p;
      m_run[r] = m_new;
    }
  }
  float a_sum = 0.0f;
  if (lr == 0) {
#pragma unroll
    for (int r = 0; r < 4; ++r)
      a_sum += m_run[r] + __logf(l_run[r]);
  }
#pragma unroll
  for (int msk = 1; msk <= 32; msk <<= 1)
    a_sum += __shfl_xor(a_sum, msk);
  if (lane == 0) atomicAdd(out, -8.0f * a_sum);
}

// ---------------- launch -----------------------------------------------------
extern "C" void kernel_launch(void* const* d_in, const int* in_sizes, int n_in,
                              void* d_out, int out_size, void* d_ws, size_t ws_size,
                              hipStream_t stream) {
  const float* g  = (const float*)d_in[0];
  const float* Wq = (const float*)d_in[1];
  const float* Wk = (const float*)d_in[2];
  float* out = (float*)d_out;

  __hip_bfloat16* gB = (__hip_bfloat16*)d_ws;                    // [2048][768]
  __hip_bfloat16* wB = gB + G_ELEMS;                             // [1536][768]
  __hip_bfloat16* QK = wB + 2 * W1_ELEMS;                        // [2048][1536]

  hipMemsetAsync(d_out, 0, sizeof(float), stream);

  // convert: (1572864 + 2*589824)/4 = 688128 quads / 256 = 2688 blocks
  convert_kernel<<<2688, 256, 0, stream>>>(g, Wq, Wk, gB, wB);
  proj_kernel<<<dim3(16, 12), 256, 0, stream>>>(gB, wB, QK);
  attn_kernel<<<dim3(32, 12), 256, 0, stream>>>(QK, out);
}

// Round 3
// 106.834 us; speedup vs baseline: 1.5184x; 1.5184x over previous
//
#include <hip/hip_runtime.h>
#include <hip/hip_bf16.h>

// N=2048, D=768, H=12, Y=64. W = [Wq;Wk] as [1536][768].
#define NN 2048
#define DD 768
#define HH 12
#define HW 1536
#define G_ELEMS (NN*DD)           // 1572864
#define W1_ELEMS (HH*64*DD)       // 589824
#define SPLITS 4
#define KPW (NN/SPLITS)           // 512 k-rows per split

typedef __attribute__((ext_vector_type(8))) short bf16x8;
typedef __attribute__((ext_vector_type(4))) float f32x4;

// native v_exp_f32 / v_log_f32 (both base-2). Avoid __exp2f/__log2f which
// collide with glibc math.h reserved identifiers under -x hip.
__device__ __forceinline__ float exp2g(float x) { return __builtin_amdgcn_exp2f(x); }
__device__ __forceinline__ float log2g(float x) { return __builtin_amdgcn_logf(x); }

// ---------------- Kernel 1: fp32 -> bf16 convert -----------------------------
// Fold beta*log2(e) = 0.125*1.4426950408889634 into Wq so scores are in
// base-2 units and exp2g needs no pre-multiply.
#define QSCALE 0.18033688011112042f
__global__ __launch_bounds__(256) void convert_kernel(
    const float* __restrict__ g, const float* __restrict__ Wq,
    const float* __restrict__ Wk, __hip_bfloat16* __restrict__ gB,
    __hip_bfloat16* __restrict__ wB) {
  int base = (blockIdx.x * 256 + threadIdx.x) * 4;
  float4 v;
  __hip_bfloat16* dst;
  if (base < G_ELEMS) {
    v = *reinterpret_cast<const float4*>(g + base);
    dst = gB + base;
  } else if (base < G_ELEMS + W1_ELEMS) {
    int o = base - G_ELEMS;
    v = *reinterpret_cast<const float4*>(Wq + o);
    v.x *= QSCALE; v.y *= QSCALE; v.z *= QSCALE; v.w *= QSCALE;
    dst = wB + o;
  } else {
    int o = base - (G_ELEMS + W1_ELEMS);
    v = *reinterpret_cast<const float4*>(Wk + o);
    dst = wB + W1_ELEMS + o;
  }
  __hip_bfloat16 h0 = __float2bfloat16(v.x), h1 = __float2bfloat16(v.y);
  __hip_bfloat16 h2 = __float2bfloat16(v.z), h3 = __float2bfloat16(v.w);
  ushort4 u;
  u.x = *reinterpret_cast<unsigned short*>(&h0);
  u.y = *reinterpret_cast<unsigned short*>(&h1);
  u.z = *reinterpret_cast<unsigned short*>(&h2);
  u.w = *reinterpret_cast<unsigned short*>(&h3);
  *reinterpret_cast<ushort4*>(dst) = u;
}

// ---------------- Kernel 2: QK projection GEMM (bf16 MFMA) -------------------
// C[2048][1536] = gB[2048][768] * wB[1536][768]^T
// 64x64 tile, BK=64, grid (32,24)=768 blocks (3/CU). 4 waves in 2x2, each
// computes 32x32 as 2x2 frags of 16x16x32.
#define LDP 72   // 64 + 8 pad: frag-read word addr stride 36/row -> 2-way max (free, m136)
__global__ __launch_bounds__(256) void proj_kernel(
    const __hip_bfloat16* __restrict__ gB, const __hip_bfloat16* __restrict__ wB,
    __hip_bfloat16* __restrict__ QK) {
  __shared__ __align__(16) __hip_bfloat16 As[64 * LDP];
  __shared__ __align__(16) __hip_bfloat16 Bs[64 * LDP];
  const int t = threadIdx.x;
  const int wave = t >> 6, lane = t & 63;
  const int lr = lane & 15, lg = lane >> 4;
  const int wm = wave & 1, wn = wave >> 1;
  const int bm = blockIdx.x, bn = blockIdx.y;

  f32x4 acc[2][2] = {};

  for (int kt = 0; kt < DD; kt += 64) {
    __syncthreads();
#pragma unroll
    for (int i = 0; i < 2; ++i) {
      int c = t + i * 256;                 // 512 chunks of 8 bf16
      int row = c >> 3, seg = (c & 7) * 8;
      uint4 va = *reinterpret_cast<const uint4*>(gB + (bm * 64 + row) * DD + kt + seg);
      *reinterpret_cast<uint4*>(&As[row * LDP + seg]) = va;
      uint4 vb = *reinterpret_cast<const uint4*>(wB + (bn * 64 + row) * DD + kt + seg);
      *reinterpret_cast<uint4*>(&Bs[row * LDP + seg]) = vb;
    }
    __syncthreads();
#pragma unroll
    for (int ks = 0; ks < 2; ++ks) {
      bf16x8 a[2], b[2];
#pragma unroll
      for (int mt = 0; mt < 2; ++mt)
        a[mt] = *reinterpret_cast<const bf16x8*>(&As[(wm * 32 + mt * 16 + lr) * LDP + ks * 32 + lg * 8]);
#pragma unroll
      for (int nt = 0; nt < 2; ++nt)
        b[nt] = *reinterpret_cast<const bf16x8*>(&Bs[(wn * 32 + nt * 16 + lr) * LDP + ks * 32 + lg * 8]);
#pragma unroll
      for (int mt = 0; mt < 2; ++mt)
#pragma unroll
        for (int nt = 0; nt < 2; ++nt)
          acc[mt][nt] = __builtin_amdgcn_mfma_f32_16x16x32_bf16(a[mt], b[nt], acc[mt][nt], 0, 0, 0);
    }
  }
#pragma unroll
  for (int mt = 0; mt < 2; ++mt) {
    int row = bm * 64 + wm * 32 + mt * 16 + lg * 4;
#pragma unroll
    for (int nt = 0; nt < 2; ++nt) {
      int col = bn * 64 + wn * 32 + nt * 16 + lr;
#pragma unroll
      for (int r = 0; r < 4; ++r)
        QK[(row + r) * HW + col] = __float2bfloat16(acc[mt][nt][r]);
    }
  }
}

// ---------------- Kernel 3: scores + per-lane online logsumexp (base-2) ------
// grid (32 q-tiles, 12 heads, 4 k-splits); block 256 = 4 waves; wave w owns
// q rows w*16..w*16+15. Each LANE keeps private (m,l) over its k-subset
// (k = kc + nt*16 + lr) -> zero cross-lane ops in the K loop.
#define LDA 72
__global__ __launch_bounds__(256) void attn_kernel(
    const __hip_bfloat16* __restrict__ QK, float2* __restrict__ part) {
  __shared__ __align__(16) __hip_bfloat16 Qs[64 * LDA];
  __shared__ __align__(16) __hip_bfloat16 Ks[64 * LDA];
  const int t = threadIdx.x;
  const int wave = t >> 6, lane = t & 63;
  const int lr = lane & 15, lg = lane >> 4;
  const int q0 = blockIdx.x * 64, h = blockIdx.y, sp = blockIdx.z;
  const int k0 = sp * KPW;

#pragma unroll
  for (int i = 0; i < 2; ++i) {
    int c = t + i * 256;
    int row = c >> 3, seg = (c & 7) * 8;
    uint4 v = *reinterpret_cast<const uint4*>(QK + (q0 + row) * HW + h * 64 + seg);
    *reinterpret_cast<uint4*>(&Qs[row * LDA + seg]) = v;
  }
  __syncthreads();
  bf16x8 aq[2];
#pragma unroll
  for (int z = 0; z < 2; ++z)
    aq[z] = *reinterpret_cast<const bf16x8*>(&Qs[(wave * 16 + lr) * LDA + z * 32 + lg * 8]);

  float m[4], l[4];
#pragma unroll
  for (int r = 0; r < 4; ++r) { m[r] = -3.0e38f; l[r] = 0.0f; }

  for (int kc = k0; kc < k0 + KPW; kc += 64) {
    __syncthreads();
#pragma unroll
    for (int i = 0; i < 2; ++i) {
      int c = t + i * 256;
      int row = c >> 3, seg = (c & 7) * 8;
      uint4 v = *reinterpret_cast<const uint4*>(QK + (kc + row) * HW + DD + h * 64 + seg);
      *reinterpret_cast<uint4*>(&Ks[row * LDA + seg]) = v;
    }
    __syncthreads();
    f32x4 s[4] = {};
#pragma unroll
    for (int nt = 0; nt < 4; ++nt)
#pragma unroll
      for (int z = 0; z < 2; ++z) {
        bf16x8 b = *reinterpret_cast<const bf16x8*>(&Ks[(nt * 16 + lr) * LDA + z * 32 + lg * 8]);
        s[nt] = __builtin_amdgcn_mfma_f32_16x16x32_bf16(aq[z], b, s[nt], 0, 0, 0);
      }
    // per-lane online update; scores already in base-2 units
#pragma unroll
    for (int r = 0; r < 4; ++r) {
      float v0 = s[0][r], v1 = s[1][r], v2 = s[2][r], v3 = s[3][r];
      float cm = fmaxf(fmaxf(v0, v1), fmaxf(v2, v3));
      float mn = fmaxf(m[r], cm);
      float p = exp2g(v0 - mn) + exp2g(v1 - mn) +
                exp2g(v2 - mn) + exp2g(v3 - mn);
      l[r] = l[r] * exp2g(m[r] - mn) + p;
      m[r] = mn;
    }
  }
  // butterfly merge across the 16 lr-lanes (lg bits untouched)
#pragma unroll
  for (int msk = 1; msk <= 8; msk <<= 1) {
#pragma unroll
    for (int r = 0; r < 4; ++r) {
      float mo = __shfl_xor(m[r], msk);
      float lo = __shfl_xor(l[r], msk);
      float mn = fmaxf(m[r], mo);
      l[r] = l[r] * exp2g(m[r] - mn) + lo * exp2g(mo - mn);
      m[r] = mn;
    }
  }
  if (lr == 0) {
#pragma unroll
    for (int r = 0; r < 4; ++r) {
      int q = q0 + wave * 16 + lg * 4 + r;
      part[(sp * HH + h) * NN + q] = make_float2(m[r], l[r]);
    }
  }
}

// ---------------- Kernel 4: merge splits + global sum ------------------------
__global__ __launch_bounds__(256) void reduce_kernel(
    const float2* __restrict__ part, float* __restrict__ out) {
  const int t = threadIdx.x;
  const int row = blockIdx.x * 256 + t;          // 0..24575 = h*2048+q
  float2 p0 = part[row];
  float2 p1 = part[24576 + row];
  float2 p2 = part[49152 + row];
  float2 p3 = part[73728 + row];
  float m = fmaxf(fmaxf(p0.x, p1.x), fmaxf(p2.x, p3.x));
  float l = p0.y * exp2g(p0.x - m) + p1.y * exp2g(p1.x - m) +
            p2.y * exp2g(p2.x - m) + p3.y * exp2g(p3.x - m);
  float lse = m + log2g(l);                      // base-2 lse
#pragma unroll
  for (int msk = 1; msk <= 32; msk <<= 1)
    lse += __shfl_xor(lse, msk);
  __shared__ float wsum[4];
  if ((t & 63) == 0) wsum[t >> 6] = lse;
  __syncthreads();
  if (t == 0)
    atomicAdd(out, -5.545177444479562f * (wsum[0] + wsum[1] + wsum[2] + wsum[3]));
}

// ---------------- launch -----------------------------------------------------
extern "C" void kernel_launch(void* const* d_in, const int* in_sizes, int n_in,
                              void* d_out, int out_size, void* d_ws, size_t ws_size,
                              hipStream_t stream) {
  const float* g  = (const float*)d_in[0];
  const float* Wq = (const float*)d_in[1];
  const float* Wk = (const float*)d_in[2];
  float* out = (float*)d_out;

  __hip_bfloat16* gB = (__hip_bfloat16*)d_ws;        // [2048][768]  (3.1 MB)
  __hip_bfloat16* wB = gB + G_ELEMS;                 // [1536][768]  (2.4 MB)
  __hip_bfloat16* QK = wB + 2 * W1_ELEMS;            // [2048][1536] (6.3 MB)
  // partials alias gB: gB is dead after proj_kernel (stream-ordered), and
  // 4*12*2048*8B = 786 KB < 3.1 MB.
  float2* part = (float2*)gB;

  (void)hipMemsetAsync(d_out, 0, sizeof(float), stream);
  convert_kernel<<<2688, 256, 0, stream>>>(g, Wq, Wk, gB, wB);
  proj_kernel<<<dim3(32, 24), 256, 0, stream>>>(gB, wB, QK);
  attn_kernel<<<dim3(32, HH, SPLITS), 256, 0, stream>>>(QK, part);
  reduce_kernel<<<96, 256, 0, stream>>>(part, out);
}